// Round 3
// baseline (17865.034 us; speedup 1.0000x reference)
//
#include <hip/hip_runtime.h>
#include <math.h>

#define T_ 512
#define B_ 64
#define I_ 512
#define H_ 512
#define G_ 2048   // 4*H
#define K_ 1024   // I + H
#define NBLK 32   // persistent workgroups

typedef __bf16 bf16x8 __attribute__((ext_vector_type(8)));
typedef float f32x4 __attribute__((ext_vector_type(4)));

// Workspace layout (bytes):
//   Whi bf16 [G_][K_]   : 4 MB    (hi part of [W_ih | W_hh])
//   Wlo bf16 [G_][K_]   : 4 MB    (lo residual)
//   bias f32 [G_]       : 8 KB
//   hswz bf16 [2][64KB] : 128 KB  (h in MFMA B-frag layout, double-buffered)
//   bar  u32            : grid barrier
//   xswz bf16 [T][64KB] : 32 MB   (x in MFMA B-frag layout)
#define OFF_WHI  ((size_t)0)
#define OFF_WLO  (OFF_WHI + (size_t)G_ * K_ * 2)
#define OFF_BIAS (OFF_WLO + (size_t)G_ * K_ * 2)
#define OFF_HSWZ (OFF_BIAS + (size_t)G_ * 4)
#define OFF_BAR  (OFF_HSWZ + (size_t)2 * H_ * B_ * 2)
#define OFF_XSWZ (OFF_BAR + 256)
// total ws use: ~8.25 MB + 32 MB ≈ 40.3 MB

// B-frag swizzle: frag-slot s = (kblk*4 + nblk)*64 + lane, holding 8 bf16:
//   quad = lane>>4, l16 = lane&15;  b = nblk*16 + l16;  k = kblk*32 + quad*8 + j
// Consumer reads one bf16x8 (16 B) per lane per frag: fully coalesced 1 KB/wave.

__global__ void prep_w(const float* __restrict__ W_ih, const float* __restrict__ W_hh,
                       const float* __restrict__ b_ih, const float* __restrict__ b_hh,
                       char* __restrict__ ws) {
    __bf16* Whi = (__bf16*)(ws + OFF_WHI);
    __bf16* Wlo = (__bf16*)(ws + OFF_WLO);
    float* bias = (float*)(ws + OFF_BIAS);
    int idx = blockIdx.x * 256 + threadIdx.x;   // over G_*K_ = 2M
    int g = idx >> 10;
    int k = idx & (K_ - 1);
    float v = (k < I_) ? W_ih[g * I_ + k] : W_hh[g * H_ + (k - I_)];
    __bf16 hi = (__bf16)v;
    Whi[idx] = hi;
    Wlo[idx] = (__bf16)(v - (float)hi);
    if (idx < G_) bias[idx] = b_ih[idx] + b_hh[idx];
    if (idx == 0) *(unsigned*)(ws + OFF_BAR) = 0u;
}

__global__ void prep_x(const float* __restrict__ input, char* __restrict__ ws) {
    __bf16* xswz = (__bf16*)(ws + OFF_XSWZ);
    // slots: T_ * 16 kblk * 4 nblk * 64 lanes = 2,097,152 ; one 16B frag-chunk each
    int s = blockIdx.x * 256 + threadIdx.x;
    int lane = s & 63;
    int nblk = (s >> 6) & 3;
    int kblk = (s >> 8) & 15;
    int t = s >> 12;
    int b = nblk * 16 + (lane & 15);
    int k = kblk * 32 + (lane >> 4) * 8;
    const float* src = input + ((size_t)t * B_ + b) * I_ + k;
    float4 v0 = *(const float4*)src;
    float4 v1 = *(const float4*)(src + 4);
    bf16x8 o;
    o[0]=(__bf16)v0.x; o[1]=(__bf16)v0.y; o[2]=(__bf16)v0.z; o[3]=(__bf16)v0.w;
    o[4]=(__bf16)v1.x; o[5]=(__bf16)v1.y; o[6]=(__bf16)v1.z; o[7]=(__bf16)v1.w;
    *(bf16x8*)(xswz + (size_t)s * 8) = o;
}

__global__ void prep_h0(const float* __restrict__ h0, char* __restrict__ ws) {
    __bf16* hswz0 = (__bf16*)(ws + OFF_HSWZ);   // parity 0: read by step t=511
    // slots: 16 hk * 4 nblk * 64 lanes = 4096
    int s = blockIdx.x * 256 + threadIdx.x;
    int lane = s & 63;
    int nblk = (s >> 6) & 3;
    int hk = s >> 8;
    int b = nblk * 16 + (lane & 15);
    int u = hk * 32 + (lane >> 4) * 8;
    const float* src = h0 + (size_t)b * H_ + u;
    float4 v0 = *(const float4*)src;
    float4 v1 = *(const float4*)(src + 4);
    bf16x8 o;
    o[0]=(__bf16)v0.x; o[1]=(__bf16)v0.y; o[2]=(__bf16)v0.z; o[3]=(__bf16)v0.w;
    o[4]=(__bf16)v1.x; o[5]=(__bf16)v1.y; o[6]=(__bf16)v1.z; o[7]=(__bf16)v1.w;
    *(bf16x8*)(hswz0 + (size_t)s * 8) = o;
}

__device__ __forceinline__ float sigmoid_f(float x) { return 1.f / (1.f + __expf(-x)); }
__device__ __forceinline__ float tanh_f(float x) { return 1.f - 2.f / (1.f + __expf(2.f * x)); }

// Persistent reverse scan. 32 WGs x 256 threads. WG wg owns hidden units
// [wg*16, wg*16+16); wave = gate type (i,f,g,o), M-tile = its 16 rows,
// all 64 batches (4 N-tiles), K=1024 (x: ks 0..15 from xswz, h: ks 16..31
// from hswz). A-fragments (weights, bf16 hi/lo) live in 256 VGPRs for the
// whole scan; B-fragments stream from the swizzled global buffers.
__launch_bounds__(256, 1)
__global__ void lstm_persist(const float* __restrict__ c0, float* out,
                             char* __restrict__ ws) {
    __shared__ float gl[4][16][65];             // [gate][unit][batch] exchange
    __shared__ __bf16 hstage[4][2][16][8];      // [nblk][lq][l16][j] -> hswz copy

    const __bf16* Whi = (const __bf16*)(ws + OFF_WHI);
    const __bf16* Wlo = (const __bf16*)(ws + OFF_WLO);
    const float* bias = (const float*)(ws + OFF_BIAS);
    __bf16* Hswz = (__bf16*)(ws + OFF_HSWZ);    // [2][32768 elements]
    const __bf16* Xswz = (const __bf16*)(ws + OFF_XSWZ);
    unsigned* bar = (unsigned*)(ws + OFF_BAR);

    const int tid = threadIdx.x;
    const int wave = tid >> 6;      // gate type
    const int lane = tid & 63;
    const int l16 = lane & 15;
    const int quad = lane >> 4;
    const int wg = blockIdx.x;

    // ---- A-fragments resident in registers: Ahi/Alo[ks], ks = k/32 over K=1024
    bf16x8 Ahi[32], Alo[32];
    {
        const size_t arow = (size_t)(wave * H_ + wg * 16 + l16) * K_ + quad * 8;
        #pragma unroll
        for (int ks = 0; ks < 32; ++ks) {
            Ahi[ks] = *(const bf16x8*)(Whi + arow + ks * 32);
            Alo[ks] = *(const bf16x8*)(Wlo + arow + ks * 32);
        }
    }

    // ---- cell-state registers: thread owns unit u = tid&15, batches rep*16+(tid>>4)
    const int cu_u = tid & 15;
    const int cu_b0 = tid >> 4;
    const int hu = wg * 16 + cu_u;
    float creg[4];
    #pragma unroll
    for (int rep = 0; rep < 4; ++rep)
        creg[rep] = c0[(size_t)(rep * 16 + cu_b0) * H_ + hu];
    const float bias_i = bias[hu];
    const float bias_f = bias[H_ + hu];
    const float bias_g = bias[2 * H_ + hu];
    const float bias_o = bias[3 * H_ + hu];
    const int lq = cu_u >> 3, jj = cu_u & 7;    // hswz producer coords

    for (int t = T_ - 1; ; --t) {
        const __bf16* xb = Xswz + (size_t)t * 32768 + lane * 8;
        const __bf16* hb = Hswz + (size_t)((t + 1) & 1) * 32768 + lane * 8;

        f32x4 acc[4] = {{0,0,0,0},{0,0,0,0},{0,0,0,0},{0,0,0,0}};

        // prefetch first 8 h-frags (hide cross-XCD latency behind x-phase)
        bf16x8 hh[8];
        #pragma unroll
        for (int i = 0; i < 8; ++i) hh[i] = *(const bf16x8*)(hb + i * 512);

        // x-phase: ks 0..15 (frag f = ks*4 + nt, stride 512 elements)
        #pragma unroll
        for (int f = 0; f < 64; ++f) {
            bf16x8 b = *(const bf16x8*)(xb + f * 512);
            const int ks = f >> 2, nt = f & 3;
            acc[nt] = __builtin_amdgcn_mfma_f32_16x16x32_bf16(Ahi[ks], b, acc[nt], 0, 0, 0);
            acc[nt] = __builtin_amdgcn_mfma_f32_16x16x32_bf16(Alo[ks], b, acc[nt], 0, 0, 0);
        }
        // h-phase: ks 16..31
        #pragma unroll
        for (int f = 0; f < 64; ++f) {
            bf16x8 b = (f < 8) ? hh[f] : *(const bf16x8*)(hb + f * 512);
            const int ks = 16 + (f >> 2), nt = f & 3;
            acc[nt] = __builtin_amdgcn_mfma_f32_16x16x32_bf16(Ahi[ks], b, acc[nt], 0, 0, 0);
            acc[nt] = __builtin_amdgcn_mfma_f32_16x16x32_bf16(Alo[ks], b, acc[nt], 0, 0, 0);
        }

        // C/D layout: col(batch) = lane&15 (+16*nt), row(unit) = quad*4 + reg
        #pragma unroll
        for (int r = 0; r < 4; ++r)
            #pragma unroll
            for (int nt = 0; nt < 4; ++nt)
                gl[wave][quad * 4 + r][nt * 16 + l16] = acc[nt][r];
        __syncthreads();

        // cell update: 4 cells per thread
        float* outt = out + (size_t)t * (B_ * H_);
        #pragma unroll
        for (int rep = 0; rep < 4; ++rep) {
            int b = rep * 16 + cu_b0;
            float ig = sigmoid_f(gl[0][cu_u][b] + bias_i);
            float fg = sigmoid_f(gl[1][cu_u][b] + bias_f);
            float gg = tanh_f(gl[2][cu_u][b] + bias_g);
            float og = sigmoid_f(gl[3][cu_u][b] + bias_o);
            float cn = fg * creg[rep] + ig * gg;
            creg[rep] = cn;
            float hn = og * tanh_f(cn);
            outt[(size_t)b * H_ + hu] = hn;
            hstage[b >> 4][lq][b & 15][jj] = (__bf16)hn;
            if (t == 0) {
                out[(size_t)T_ * B_ * H_ + (size_t)b * H_ + hu] = hn;                 // h_f
                out[(size_t)T_ * B_ * H_ + B_ * H_ + (size_t)b * H_ + hu] = cn;       // c_f
            }
        }

        if (t == 0) break;

        __syncthreads();   // hstage complete
        // publish h frags to hswz[t&1]: WG covers hk = wg>>1, quads q0..q0+1
        if (tid < 128) {
            int nblk = tid >> 5, lqc = (tid >> 4) & 1, l16c = tid & 15;
            bf16x8 v = *(bf16x8*)((__bf16*)hstage + tid * 8);
            int hk = wg >> 1, q0 = (wg & 1) * 2;
            size_t off = (size_t)(((hk * 4 + nblk) * 64 + (q0 + lqc) * 16 + l16c)) * 8;
            *(bf16x8*)(Hswz + (size_t)(t & 1) * 32768 + off) = v;
        }

        // ---- grid barrier (release h writes of step t, acquire for step t-1)
        __syncthreads();
        if (tid == 0) {
            __threadfence();
            __hip_atomic_fetch_add(bar, 1u, __ATOMIC_RELEASE, __HIP_MEMORY_SCOPE_AGENT);
            const unsigned target = (unsigned)(T_ - t) * NBLK;
            while (__hip_atomic_load(bar, __ATOMIC_ACQUIRE, __HIP_MEMORY_SCOPE_AGENT) < target)
                __builtin_amdgcn_s_sleep(1);
            __threadfence();
        }
        __syncthreads();
    }
}

extern "C" void kernel_launch(void* const* d_in, const int* in_sizes, int n_in,
                              void* d_out, int out_size, void* d_ws, size_t ws_size,
                              hipStream_t stream) {
    const float* input = (const float*)d_in[0];
    const float* h0   = (const float*)d_in[1];
    const float* c0   = (const float*)d_in[2];
    const float* W_ih = (const float*)d_in[3];
    const float* W_hh = (const float*)d_in[4];
    const float* b_ih = (const float*)d_in[5];
    const float* b_hh = (const float*)d_in[6];
    float* out = (float*)d_out;
    char* ws = (char*)d_ws;

    prep_w<<<(G_ * K_) / 256, 256, 0, stream>>>(W_ih, W_hh, b_ih, b_hh, ws);
    prep_x<<<(T_ * I_ * B_ / 8) / 256, 256, 0, stream>>>(input, ws);
    prep_h0<<<(H_ / 32) * (B_ / 16) * 64 / 256, 256, 0, stream>>>(h0, ws);
    lstm_persist<<<NBLK, 256, 0, stream>>>(c0, out, ws);
}

// Round 4
// 10508.363 us; speedup vs baseline: 1.7001x; 1.7001x over previous
//
#include <hip/hip_runtime.h>
#include <math.h>

#define T_ 512
#define B_ 64
#define I_ 512
#define H_ 512
#define G_ 2048   // 4*H
#define K_ 1024   // I + H
#define NBLK 32   // persistent workgroups

typedef __bf16 bf16x8 __attribute__((ext_vector_type(8)));
typedef float f32x4 __attribute__((ext_vector_type(4)));
typedef int i32x4 __attribute__((ext_vector_type(4)));

// Workspace layout (bytes):
//   Whi bf16 [G_][K_]   : 4 MB    (hi part of [W_ih | W_hh])
//   Wlo bf16 [G_][K_]   : 4 MB    (lo residual)
//   bias f32 [G_]       : 8 KB
//   hswz bf16 [2][64KB] : 128 KB  (h in MFMA B-frag layout, double-buffered,
//                                  written sc0sc1 -> L3-coherent, read L2-bypassing)
//   bar  u32            : grid barrier (monotone counter)
//   xswz bf16 [T][64KB] : 32 MB   (x in MFMA B-frag layout, read cached)
#define OFF_WHI  ((size_t)0)
#define OFF_WLO  (OFF_WHI + (size_t)G_ * K_ * 2)
#define OFF_BIAS (OFF_WLO + (size_t)G_ * K_ * 2)
#define OFF_HSWZ (OFF_BIAS + (size_t)G_ * 4)
#define OFF_BAR  (OFF_HSWZ + (size_t)2 * H_ * B_ * 2)
#define OFF_XSWZ (OFF_BAR + 256)

// B-frag swizzle: frag-slot s = (kblk*4 + nblk)*64 + lane, holding 8 bf16:
//   quad = lane>>4, l16 = lane&15;  b = nblk*16 + l16;  k = kblk*32 + quad*8 + j

__global__ void prep_w(const float* __restrict__ W_ih, const float* __restrict__ W_hh,
                       const float* __restrict__ b_ih, const float* __restrict__ b_hh,
                       char* __restrict__ ws) {
    __bf16* Whi = (__bf16*)(ws + OFF_WHI);
    __bf16* Wlo = (__bf16*)(ws + OFF_WLO);
    float* bias = (float*)(ws + OFF_BIAS);
    int idx = blockIdx.x * 256 + threadIdx.x;   // over G_*K_ = 2M
    int g = idx >> 10;
    int k = idx & (K_ - 1);
    float v = (k < I_) ? W_ih[g * I_ + k] : W_hh[g * H_ + (k - I_)];
    __bf16 hi = (__bf16)v;
    Whi[idx] = hi;
    Wlo[idx] = (__bf16)(v - (float)hi);
    if (idx < G_) bias[idx] = b_ih[idx] + b_hh[idx];
    if (idx == 0) *(unsigned*)(ws + OFF_BAR) = 0u;
}

__global__ void prep_x(const float* __restrict__ input, char* __restrict__ ws) {
    __bf16* xswz = (__bf16*)(ws + OFF_XSWZ);
    int s = blockIdx.x * 256 + threadIdx.x;   // frag-chunk id
    int lane = s & 63;
    int nblk = (s >> 6) & 3;
    int kblk = (s >> 8) & 15;
    int t = s >> 12;
    int b = nblk * 16 + (lane & 15);
    int k = kblk * 32 + (lane >> 4) * 8;
    const float* src = input + ((size_t)t * B_ + b) * I_ + k;
    float4 v0 = *(const float4*)src;
    float4 v1 = *(const float4*)(src + 4);
    bf16x8 o;
    o[0]=(__bf16)v0.x; o[1]=(__bf16)v0.y; o[2]=(__bf16)v0.z; o[3]=(__bf16)v0.w;
    o[4]=(__bf16)v1.x; o[5]=(__bf16)v1.y; o[6]=(__bf16)v1.z; o[7]=(__bf16)v1.w;
    *(bf16x8*)(xswz + (size_t)s * 8) = o;
}

__global__ void prep_h0(const float* __restrict__ h0, char* __restrict__ ws) {
    __bf16* hswz0 = (__bf16*)(ws + OFF_HSWZ);   // parity 0: read by step t=511
    int s = blockIdx.x * 256 + threadIdx.x;
    int lane = s & 63;
    int nblk = (s >> 6) & 3;
    int hk = s >> 8;
    int b = nblk * 16 + (lane & 15);
    int u = hk * 32 + (lane >> 4) * 8;
    const float* src = h0 + (size_t)b * H_ + u;
    float4 v0 = *(const float4*)src;
    float4 v1 = *(const float4*)(src + 4);
    bf16x8 o;
    o[0]=(__bf16)v0.x; o[1]=(__bf16)v0.y; o[2]=(__bf16)v0.z; o[3]=(__bf16)v0.w;
    o[4]=(__bf16)v1.x; o[5]=(__bf16)v1.y; o[6]=(__bf16)v1.z; o[7]=(__bf16)v1.w;
    *(bf16x8*)(hswz0 + (size_t)s * 8) = o;
}

__device__ __forceinline__ float sigmoid_f(float x) { return 1.f / (1.f + __expf(-x)); }
__device__ __forceinline__ float tanh_f(float x) { return 1.f - 2.f / (1.f + __expf(2.f * x)); }

// Persistent reverse scan, 32 WGs x 256 threads (1 WG/CU). WG wg owns hidden
// units [wg*16, wg*16+16); wave = gate type. Per step: h staged to LDS via
// async DMA (L2-bypassing), 128 h-MFMAs; x contribution for the NEXT step is
// precomputed between barrier-add and spin (hidden behind stragglers).
__launch_bounds__(256, 1)
__global__ void lstm_persist(const float* __restrict__ c0, float* out,
                             char* __restrict__ ws) {
    __shared__ __bf16 hbuf[32768];              // h frags, 64 KB
    __shared__ float gl[4][16][66];             // [gate][unit][batch] exchange
    __shared__ __bf16 hstage[4][2][16][8];      // [nblk][lq][l16][j]

    const __bf16* Whi = (const __bf16*)(ws + OFF_WHI);
    const __bf16* Wlo = (const __bf16*)(ws + OFF_WLO);
    const float* bias = (const float*)(ws + OFF_BIAS);
    __bf16* Hswz = (__bf16*)(ws + OFF_HSWZ);    // [2][32768 elements]
    const __bf16* Xswz = (const __bf16*)(ws + OFF_XSWZ);
    unsigned* bar = (unsigned*)(ws + OFF_BAR);

    const int tid = threadIdx.x;
    const int wave = tid >> 6;      // gate type
    const int lane = tid & 63;
    const int l16 = lane & 15;
    const int quad = lane >> 4;
    const int wg = blockIdx.x;

    // ---- A-fragments resident (VGPR/AGPR): ks 0..15 = W_ih cols, 16..31 = W_hh
    bf16x8 Ahi[32], Alo[32];
    {
        const size_t arow = (size_t)(wave * H_ + wg * 16 + l16) * K_ + quad * 8;
        #pragma unroll
        for (int ks = 0; ks < 32; ++ks) {
            Ahi[ks] = *(const bf16x8*)(Whi + arow + ks * 32);
            Alo[ks] = *(const bf16x8*)(Wlo + arow + ks * 32);
        }
    }

    // ---- cell state in registers: thread owns unit u = tid&15, batches rep*16+(tid>>4)
    const int cu_u = tid & 15;
    const int cu_b0 = tid >> 4;
    const int hu = wg * 16 + cu_u;
    float creg[4];
    #pragma unroll
    for (int rep = 0; rep < 4; ++rep)
        creg[rep] = c0[(size_t)(rep * 16 + cu_b0) * H_ + hu];
    const float bias_i = bias[hu];
    const float bias_f = bias[H_ + hu];
    const float bias_g = bias[2 * H_ + hu];
    const float bias_o = bias[3 * H_ + hu];
    const int lq = cu_u >> 3, jj = cu_u & 7;    // hstage producer coords

    // ---- x contribution for t=511
    f32x4 acc[4] = {{0,0,0,0},{0,0,0,0},{0,0,0,0},{0,0,0,0}};
    {
        const __bf16* xb = Xswz + (size_t)(T_ - 1) * 32768 + lane * 8;
        #pragma unroll
        for (int f = 0; f < 64; ++f) {
            bf16x8 b = *(const bf16x8*)(xb + f * 512);
            const int ks = f >> 2, nt = f & 3;
            acc[nt] = __builtin_amdgcn_mfma_f32_16x16x32_bf16(Ahi[ks], b, acc[nt], 0, 0, 0);
            acc[nt] = __builtin_amdgcn_mfma_f32_16x16x32_bf16(Alo[ks], b, acc[nt], 0, 0, 0);
        }
    }

    for (int t = T_ - 1; ; --t) {
        // ---- stage h_{t+1} frags into LDS: 64 x 1KB async DMA, L2-bypassing
        {
            const __bf16* hb = Hswz + (size_t)((t + 1) & 1) * 32768;
            const int n0 = wave * 16;
            #pragma unroll
            for (int i = 0; i < 16; ++i) {
                const int n = n0 + i;
                __builtin_amdgcn_global_load_lds(
                    (const __attribute__((address_space(1))) void*)(hb + (size_t)n * 512 + lane * 8),
                    (__attribute__((address_space(3))) void*)(hbuf + n * 512),
                    16, 0, 0x11 /* sc0|sc1 */);
            }
        }
        asm volatile("s_waitcnt vmcnt(0)" ::: "memory");
        __syncthreads();

        // ---- h-phase: 64 frags from LDS, hi/lo MFMA into acc (which holds x(t))
        #pragma unroll
        for (int f = 0; f < 64; ++f) {
            bf16x8 b = *(const bf16x8*)(hbuf + f * 512 + lane * 8);
            const int ks = 16 + (f >> 2), nt = f & 3;
            acc[nt] = __builtin_amdgcn_mfma_f32_16x16x32_bf16(Ahi[ks], b, acc[nt], 0, 0, 0);
            acc[nt] = __builtin_amdgcn_mfma_f32_16x16x32_bf16(Alo[ks], b, acc[nt], 0, 0, 0);
        }

        // ---- exchange gates: col(batch) = lane&15 (+16*nt), row(unit) = quad*4 + reg
        #pragma unroll
        for (int r = 0; r < 4; ++r)
            #pragma unroll
            for (int nt = 0; nt < 4; ++nt)
                gl[wave][quad * 4 + r][nt * 16 + l16] = acc[nt][r];
        __syncthreads();

        // ---- cell update: 4 cells per thread
        float* outt = out + (size_t)t * (B_ * H_);
        #pragma unroll
        for (int rep = 0; rep < 4; ++rep) {
            int b = rep * 16 + cu_b0;
            float ig = sigmoid_f(gl[0][cu_u][b] + bias_i);
            float fg = sigmoid_f(gl[1][cu_u][b] + bias_f);
            float gg = tanh_f(gl[2][cu_u][b] + bias_g);
            float og = sigmoid_f(gl[3][cu_u][b] + bias_o);
            float cn = fg * creg[rep] + ig * gg;
            creg[rep] = cn;
            float hn = og * tanh_f(cn);
            outt[(size_t)b * H_ + hu] = hn;
            hstage[b >> 4][lq][b & 15][jj] = (__bf16)hn;
            if (t == 0) {
                out[(size_t)T_ * B_ * H_ + (size_t)b * H_ + hu] = hn;               // h_f
                out[(size_t)T_ * B_ * H_ + B_ * H_ + (size_t)b * H_ + hu] = cn;     // c_f
            }
        }

        if (t == 0) break;

        __syncthreads();   // hstage complete
        // ---- publish h_t frags: sc0 sc1 stores (write-through to L3)
        if (tid < 128) {
            i32x4 v = *(i32x4*)((__bf16*)hstage + tid * 8);
            const int nblk = tid >> 5, lqc = (tid >> 4) & 1, l16c = tid & 15;
            const int hk = wg >> 1, q0 = (wg & 1) * 2;
            size_t off = (size_t)(((hk * 4 + nblk) * 64 + (q0 + lqc) * 16 + l16c)) * 8;
            __bf16* dst = Hswz + (size_t)(t & 1) * 32768 + off;
            asm volatile("global_store_dwordx4 %0, %1, off sc0 sc1"
                         :: "v"(dst), "v"(v) : "memory");
        }
        asm volatile("s_waitcnt vmcnt(0)" ::: "memory");   // per-wave store drain
        __syncthreads();                                    // all waves' stores done

        if (tid == 0)
            __hip_atomic_fetch_add(bar, 1u, __ATOMIC_RELAXED, __HIP_MEMORY_SCOPE_AGENT);

        // ---- x contribution for step t-1 (cached loads; hidden behind stragglers)
        #pragma unroll
        for (int nt = 0; nt < 4; ++nt) acc[nt] = (f32x4){0, 0, 0, 0};
        {
            const __bf16* xb = Xswz + (size_t)(t - 1) * 32768 + lane * 8;
            #pragma unroll
            for (int f = 0; f < 64; ++f) {
                bf16x8 b = *(const bf16x8*)(xb + f * 512);
                const int ks = f >> 2, nt = f & 3;
                acc[nt] = __builtin_amdgcn_mfma_f32_16x16x32_bf16(Ahi[ks], b, acc[nt], 0, 0, 0);
                acc[nt] = __builtin_amdgcn_mfma_f32_16x16x32_bf16(Alo[ks], b, acc[nt], 0, 0, 0);
            }
        }

        // ---- relaxed spin (no per-poll invalidates)
        if (tid == 0) {
            const unsigned target = (unsigned)(T_ - t) * NBLK;
            while (__hip_atomic_load(bar, __ATOMIC_RELAXED, __HIP_MEMORY_SCOPE_AGENT) < target)
                __builtin_amdgcn_s_sleep(1);
        }
        __syncthreads();
    }
}

extern "C" void kernel_launch(void* const* d_in, const int* in_sizes, int n_in,
                              void* d_out, int out_size, void* d_ws, size_t ws_size,
                              hipStream_t stream) {
    const float* input = (const float*)d_in[0];
    const float* h0   = (const float*)d_in[1];
    const float* c0   = (const float*)d_in[2];
    const float* W_ih = (const float*)d_in[3];
    const float* W_hh = (const float*)d_in[4];
    const float* b_ih = (const float*)d_in[5];
    const float* b_hh = (const float*)d_in[6];
    float* out = (float*)d_out;
    char* ws = (char*)d_ws;

    prep_w<<<(G_ * K_) / 256, 256, 0, stream>>>(W_ih, W_hh, b_ih, b_hh, ws);
    prep_x<<<(T_ * I_ * B_ / 8) / 256, 256, 0, stream>>>(input, ws);
    prep_h0<<<(H_ / 32) * (B_ / 16) * 64 / 256, 256, 0, stream>>>(h0, ws);
    lstm_persist<<<NBLK, 256, 0, stream>>>(c0, out, ws);
}

// Round 5
// 5616.821 us; speedup vs baseline: 3.1806x; 1.8709x over previous
//
#include <hip/hip_runtime.h>
#include <math.h>
#include <stdint.h>

#define T_ 512
#define B_ 64
#define I_ 512
#define H_ 512
#define G_ 2048   // 4*H
#define K_ 1024   // I + H
#define NBLK 32   // persistent workgroups

typedef __bf16 bf16x8 __attribute__((ext_vector_type(8)));
typedef float f32x4 __attribute__((ext_vector_type(4)));
typedef int i32x4 __attribute__((ext_vector_type(4)));

// Workspace layout (bytes):
//   W bf16 [G_][K_]     : 4 MB    ([W_ih | W_hh], bf16)
//   bias f32 [G_]       : 8 KB
//   hswz bf16 [2][64KB] : 128 KB  (h in MFMA B-frag layout, double-buffered,
//                                  written sc0sc1 -> L3-coherent, read L2-bypassing)
//   bar  u32            : grid barrier (monotone counter)
//   xswz bf16 [T][64KB] : 32 MB   (x in MFMA B-frag layout, read cached)
#define OFF_W    ((size_t)0)
#define OFF_BIAS (OFF_W + (size_t)G_ * K_ * 2)
#define OFF_HSWZ (OFF_BIAS + (size_t)G_ * 4)
#define OFF_BAR  (OFF_HSWZ + (size_t)2 * H_ * B_ * 2)
#define OFF_XSWZ (OFF_BAR + 256)

// B-frag swizzle: frag-slot s = (kblk*4 + nblk)*64 + lane, holding 8 bf16:
//   quad = lane>>4, l16 = lane&15;  b = nblk*16 + l16;  k = kblk*32 + quad*8 + j

__global__ void prep_w(const float* __restrict__ W_ih, const float* __restrict__ W_hh,
                       const float* __restrict__ b_ih, const float* __restrict__ b_hh,
                       char* __restrict__ ws) {
    __bf16* W = (__bf16*)(ws + OFF_W);
    float* bias = (float*)(ws + OFF_BIAS);
    int idx = blockIdx.x * 256 + threadIdx.x;   // over G_*K_ = 2M
    int g = idx >> 10;
    int k = idx & (K_ - 1);
    float v = (k < I_) ? W_ih[g * I_ + k] : W_hh[g * H_ + (k - I_)];
    W[idx] = (__bf16)v;
    if (idx < G_) bias[idx] = b_ih[idx] + b_hh[idx];
    if (idx == 0) *(unsigned*)(ws + OFF_BAR) = 0u;
}

__global__ void prep_x(const float* __restrict__ input, char* __restrict__ ws) {
    __bf16* xswz = (__bf16*)(ws + OFF_XSWZ);
    int s = blockIdx.x * 256 + threadIdx.x;   // frag-chunk id
    int lane = s & 63;
    int nblk = (s >> 6) & 3;
    int kblk = (s >> 8) & 15;
    int t = s >> 12;
    int b = nblk * 16 + (lane & 15);
    int k = kblk * 32 + (lane >> 4) * 8;
    const float* src = input + ((size_t)t * B_ + b) * I_ + k;
    float4 v0 = *(const float4*)src;
    float4 v1 = *(const float4*)(src + 4);
    bf16x8 o;
    o[0]=(__bf16)v0.x; o[1]=(__bf16)v0.y; o[2]=(__bf16)v0.z; o[3]=(__bf16)v0.w;
    o[4]=(__bf16)v1.x; o[5]=(__bf16)v1.y; o[6]=(__bf16)v1.z; o[7]=(__bf16)v1.w;
    *(bf16x8*)(xswz + (size_t)s * 8) = o;
}

__global__ void prep_h0(const float* __restrict__ h0, char* __restrict__ ws) {
    __bf16* hswz0 = (__bf16*)(ws + OFF_HSWZ);   // parity 0: read by step t=511
    int s = blockIdx.x * 256 + threadIdx.x;
    int lane = s & 63;
    int nblk = (s >> 6) & 3;
    int hk = s >> 8;
    int b = nblk * 16 + (lane & 15);
    int u = hk * 32 + (lane >> 4) * 8;
    const float* src = h0 + (size_t)b * H_ + u;
    float4 v0 = *(const float4*)src;
    float4 v1 = *(const float4*)(src + 4);
    bf16x8 o;
    o[0]=(__bf16)v0.x; o[1]=(__bf16)v0.y; o[2]=(__bf16)v0.z; o[3]=(__bf16)v0.w;
    o[4]=(__bf16)v1.x; o[5]=(__bf16)v1.y; o[6]=(__bf16)v1.z; o[7]=(__bf16)v1.w;
    *(bf16x8*)(hswz0 + (size_t)s * 8) = o;
}

__device__ __forceinline__ float sigmoid_f(float x) { return 1.f / (1.f + __expf(-x)); }
__device__ __forceinline__ float tanh_f(float x) { return 1.f - 2.f / (1.f + __expf(2.f * x)); }

// Persistent reverse scan, 32 WGs x 256 threads (1 WG/CU). WG wg owns hidden
// units [wg*16, wg*16+16); wave = gate type. A-frags (bf16, 128 VGPRs) are
// register-resident for the whole scan. Per step: h staged to LDS via async
// DMA (L2-bypassing), 64 h-MFMAs; x contribution for the NEXT step computed
// between barrier-add and spin. Barrier poll = sc0sc1 load (bypasses local
// caches -> prompt observation, zero invalidation traffic).
__launch_bounds__(256, 1)
__global__ void lstm_persist(const float* __restrict__ c0, float* out,
                             char* __restrict__ ws) {
    __shared__ __bf16 hbuf[32768];              // h frags, 64 KB
    __shared__ float gl[4][16][66];             // [gate][unit][batch] exchange
    __shared__ __bf16 hstage[4][2][16][8];      // [nblk][lq][l16][j]

    const __bf16* W = (const __bf16*)(ws + OFF_W);
    const float* bias = (const float*)(ws + OFF_BIAS);
    __bf16* Hswz = (__bf16*)(ws + OFF_HSWZ);    // [2][32768 elements]
    const __bf16* Xswz = (const __bf16*)(ws + OFF_XSWZ);
    unsigned* bar = (unsigned*)(ws + OFF_BAR);

    const int tid = threadIdx.x;
    const int wave = tid >> 6;      // gate type
    const int lane = tid & 63;
    const int l16 = lane & 15;
    const int quad = lane >> 4;
    const int wg = blockIdx.x;

    // ---- A-fragments resident: ks 0..15 = W_ih cols, 16..31 = W_hh (128 VGPRs)
    bf16x8 A[32];
    {
        const size_t arow = (size_t)(wave * H_ + wg * 16 + l16) * K_ + quad * 8;
        #pragma unroll
        for (int ks = 0; ks < 32; ++ks)
            A[ks] = *(const bf16x8*)(W + arow + ks * 32);
    }

    // ---- cell state in registers: thread owns unit u = tid&15, batches rep*16+(tid>>4)
    const int cu_u = tid & 15;
    const int cu_b0 = tid >> 4;
    const int hu = wg * 16 + cu_u;
    float creg[4];
    #pragma unroll
    for (int rep = 0; rep < 4; ++rep)
        creg[rep] = c0[(size_t)(rep * 16 + cu_b0) * H_ + hu];
    const float bias_i = bias[hu];
    const float bias_f = bias[H_ + hu];
    const float bias_g = bias[2 * H_ + hu];
    const float bias_o = bias[3 * H_ + hu];
    const int lq = cu_u >> 3, jj = cu_u & 7;    // hstage producer coords

    // ---- x contribution for t=511
    f32x4 acc[4] = {{0,0,0,0},{0,0,0,0},{0,0,0,0},{0,0,0,0}};
    {
        const __bf16* xb = Xswz + (size_t)(T_ - 1) * 32768 + lane * 8;
        #pragma unroll
        for (int f = 0; f < 64; ++f) {
            bf16x8 b = *(const bf16x8*)(xb + f * 512);
            acc[f & 3] = __builtin_amdgcn_mfma_f32_16x16x32_bf16(A[f >> 2], b, acc[f & 3], 0, 0, 0);
        }
    }

    for (int t = T_ - 1; ; --t) {
        // ---- stage h_{t+1} frags into LDS: 64 x 1KB async DMA, L2-bypassing
        {
            const __bf16* hb = Hswz + (size_t)((t + 1) & 1) * 32768;
            const int n0 = wave * 16;
            #pragma unroll
            for (int i = 0; i < 16; ++i) {
                const int n = n0 + i;
                __builtin_amdgcn_global_load_lds(
                    (const __attribute__((address_space(1))) void*)(hb + (size_t)n * 512 + lane * 8),
                    (__attribute__((address_space(3))) void*)(hbuf + n * 512),
                    16, 0, 0x11 /* sc0|sc1 */);
            }
        }
        asm volatile("s_waitcnt vmcnt(0)" ::: "memory");
        __syncthreads();

        // ---- h-phase: 64 frags from LDS, MFMA into acc (which holds x(t) part)
        #pragma unroll
        for (int f = 0; f < 64; ++f) {
            bf16x8 b = *(const bf16x8*)(hbuf + f * 512 + lane * 8);
            acc[f & 3] = __builtin_amdgcn_mfma_f32_16x16x32_bf16(A[16 + (f >> 2)], b, acc[f & 3], 0, 0, 0);
        }

        // ---- exchange gates: col(batch) = lane&15 (+16*nt), row(unit) = quad*4 + reg
        #pragma unroll
        for (int r = 0; r < 4; ++r)
            #pragma unroll
            for (int nt = 0; nt < 4; ++nt)
                gl[wave][quad * 4 + r][nt * 16 + l16] = acc[nt][r];
        __syncthreads();

        // ---- cell update: 4 cells per thread
        float* outt = out + (size_t)t * (B_ * H_);
        #pragma unroll
        for (int rep = 0; rep < 4; ++rep) {
            int b = rep * 16 + cu_b0;
            float ig = sigmoid_f(gl[0][cu_u][b] + bias_i);
            float fg = sigmoid_f(gl[1][cu_u][b] + bias_f);
            float gg = tanh_f(gl[2][cu_u][b] + bias_g);
            float og = sigmoid_f(gl[3][cu_u][b] + bias_o);
            float cn = fg * creg[rep] + ig * gg;
            creg[rep] = cn;
            float hn = og * tanh_f(cn);
            outt[(size_t)b * H_ + hu] = hn;
            hstage[b >> 4][lq][b & 15][jj] = (__bf16)hn;
            if (t == 0) {
                out[(size_t)T_ * B_ * H_ + (size_t)b * H_ + hu] = hn;               // h_f
                out[(size_t)T_ * B_ * H_ + B_ * H_ + (size_t)b * H_ + hu] = cn;     // c_f
            }
        }

        if (t == 0) break;

        __syncthreads();   // hstage complete
        // ---- publish h_t frags: sc0 sc1 stores (write-through to coherence point)
        if (tid < 128) {
            i32x4 v = *(i32x4*)((__bf16*)hstage + tid * 8);
            const int nblk = tid >> 5, lqc = (tid >> 4) & 1, l16c = tid & 15;
            const int hk = wg >> 1, q0 = (wg & 1) * 2;
            size_t off = (size_t)(((hk * 4 + nblk) * 64 + (q0 + lqc) * 16 + l16c)) * 8;
            __bf16* dst = Hswz + (size_t)(t & 1) * 32768 + off;
            asm volatile("global_store_dwordx4 %0, %1, off sc0 sc1"
                         :: "v"(dst), "v"(v) : "memory");
        }
        asm volatile("s_waitcnt vmcnt(0)" ::: "memory");   // per-wave store drain
        __syncthreads();                                    // all waves' stores done

        if (tid == 0)
            __hip_atomic_fetch_add(bar, 1u, __ATOMIC_RELAXED, __HIP_MEMORY_SCOPE_AGENT);

        // ---- x contribution for step t-1 (cached loads; hidden behind stragglers)
        #pragma unroll
        for (int nt = 0; nt < 4; ++nt) acc[nt] = (f32x4){0, 0, 0, 0};
        {
            const __bf16* xb = Xswz + (size_t)(t - 1) * 32768 + lane * 8;
            #pragma unroll
            for (int f = 0; f < 64; ++f) {
                bf16x8 b = *(const bf16x8*)(xb + f * 512);
                acc[f & 3] = __builtin_amdgcn_mfma_f32_16x16x32_bf16(A[f >> 2], b, acc[f & 3], 0, 0, 0);
            }
        }

        // ---- spin with cache-bypassing poll (sc0 sc1: no invalidates, no staleness)
        if (tid == 0) {
            const unsigned target = (unsigned)(T_ - t) * NBLK;
            const unsigned long long baddr = (unsigned long long)(uintptr_t)bar;
            unsigned cur;
            do {
                asm volatile("global_load_dword %0, %1, off sc0 sc1\n\t"
                             "s_waitcnt vmcnt(0)"
                             : "=v"(cur) : "v"(baddr) : "memory");
            } while (cur < target);
        }
        __syncthreads();
    }
}

extern "C" void kernel_launch(void* const* d_in, const int* in_sizes, int n_in,
                              void* d_out, int out_size, void* d_ws, size_t ws_size,
                              hipStream_t stream) {
    const float* input = (const float*)d_in[0];
    const float* h0   = (const float*)d_in[1];
    const float* c0   = (const float*)d_in[2];
    const float* W_ih = (const float*)d_in[3];
    const float* W_hh = (const float*)d_in[4];
    const float* b_ih = (const float*)d_in[5];
    const float* b_hh = (const float*)d_in[6];
    float* out = (float*)d_out;
    char* ws = (char*)d_ws;

    prep_w<<<(G_ * K_) / 256, 256, 0, stream>>>(W_ih, W_hh, b_ih, b_hh, ws);
    prep_x<<<(T_ * I_ * B_ / 8) / 256, 256, 0, stream>>>(input, ws);
    prep_h0<<<(H_ / 32) * (B_ / 16) * 64 / 256, 256, 0, stream>>>(h0, ws);
    lstm_persist<<<NBLK, 256, 0, stream>>>(c0, out, ws);
}

// Round 6
// 2836.706 us; speedup vs baseline: 6.2978x; 1.9801x over previous
//
#include <hip/hip_runtime.h>
#include <math.h>
#include <stdint.h>

#define T_ 512
#define B_ 64
#define I_ 512
#define H_ 512
#define G_ 2048   // 4*H
#define K_ 1024   // I + H
#define NBLK 32   // persistent workgroups

typedef __bf16 bf16x8 __attribute__((ext_vector_type(8)));
typedef float f32x4 __attribute__((ext_vector_type(4)));
typedef int i32x4 __attribute__((ext_vector_type(4)));

// Workspace layout (bytes):
//   W bf16 [G_][K_]     : 4 MB    ([W_ih | W_hh], bf16)
//   bias f32 [G_]       : 8 KB
//   hswz bf16 [2][64KB] : 128 KB  (h in MFMA B-frag layout, double-buffered,
//                                  written sc0sc1, read via L2-bypassing DMA)
//   flags u32 [32]      : per-WG progress flags (monotone step counts)
//   xswz bf16 [T][64KB] : 32 MB   (x in MFMA B-frag layout, read cached)
#define OFF_W    ((size_t)0)
#define OFF_BIAS (OFF_W + (size_t)G_ * K_ * 2)
#define OFF_HSWZ (OFF_BIAS + (size_t)G_ * 4)
#define OFF_BAR  (OFF_HSWZ + (size_t)2 * H_ * B_ * 2)
#define OFF_XSWZ (OFF_BAR + 256)

// B-frag swizzle: frag-slot s = (kblk*4 + nblk)*64 + lane, holding 8 bf16:
//   quad = lane>>4, l16 = lane&15;  b = nblk*16 + l16;  k = kblk*32 + quad*8 + j

__global__ void prep_w(const float* __restrict__ W_ih, const float* __restrict__ W_hh,
                       const float* __restrict__ b_ih, const float* __restrict__ b_hh,
                       char* __restrict__ ws) {
    __bf16* W = (__bf16*)(ws + OFF_W);
    float* bias = (float*)(ws + OFF_BIAS);
    int idx = blockIdx.x * 256 + threadIdx.x;   // over G_*K_ = 2M
    int g = idx >> 10;
    int k = idx & (K_ - 1);
    float v = (k < I_) ? W_ih[g * I_ + k] : W_hh[g * H_ + (k - I_)];
    W[idx] = (__bf16)v;
    if (idx < G_) bias[idx] = b_ih[idx] + b_hh[idx];
    if (idx < 32) ((unsigned*)(ws + OFF_BAR))[idx] = 0u;
}

__global__ void prep_x(const float* __restrict__ input, char* __restrict__ ws) {
    __bf16* xswz = (__bf16*)(ws + OFF_XSWZ);
    int s = blockIdx.x * 256 + threadIdx.x;   // frag-chunk id
    int lane = s & 63;
    int nblk = (s >> 6) & 3;
    int kblk = (s >> 8) & 15;
    int t = s >> 12;
    int b = nblk * 16 + (lane & 15);
    int k = kblk * 32 + (lane >> 4) * 8;
    const float* src = input + ((size_t)t * B_ + b) * I_ + k;
    float4 v0 = *(const float4*)src;
    float4 v1 = *(const float4*)(src + 4);
    bf16x8 o;
    o[0]=(__bf16)v0.x; o[1]=(__bf16)v0.y; o[2]=(__bf16)v0.z; o[3]=(__bf16)v0.w;
    o[4]=(__bf16)v1.x; o[5]=(__bf16)v1.y; o[6]=(__bf16)v1.z; o[7]=(__bf16)v1.w;
    *(bf16x8*)(xswz + (size_t)s * 8) = o;
}

__global__ void prep_h0(const float* __restrict__ h0, char* __restrict__ ws) {
    __bf16* hswz0 = (__bf16*)(ws + OFF_HSWZ);   // parity 0: read by step t=511
    int s = blockIdx.x * 256 + threadIdx.x;
    int lane = s & 63;
    int nblk = (s >> 6) & 3;
    int hk = s >> 8;
    int b = nblk * 16 + (lane & 15);
    int u = hk * 32 + (lane >> 4) * 8;
    const float* src = h0 + (size_t)b * H_ + u;
    float4 v0 = *(const float4*)src;
    float4 v1 = *(const float4*)(src + 4);
    bf16x8 o;
    o[0]=(__bf16)v0.x; o[1]=(__bf16)v0.y; o[2]=(__bf16)v0.z; o[3]=(__bf16)v0.w;
    o[4]=(__bf16)v1.x; o[5]=(__bf16)v1.y; o[6]=(__bf16)v1.z; o[7]=(__bf16)v1.w;
    *(bf16x8*)(hswz0 + (size_t)s * 8) = o;
}

__device__ __forceinline__ float sigmoid_f(float x) { return 1.f / (1.f + __expf(-x)); }
__device__ __forceinline__ float tanh_f(float x) { return 1.f - 2.f / (1.f + __expf(2.f * x)); }

// Persistent reverse scan, 32 WGs x 256 threads (1 WG/CU, LDS-bound). WG wg
// owns hidden units [wg*16, wg*16+16); wave = gate type. A-frags (bf16, 128
// VGPRs) register-resident. Per step: poll 32 producer flags (one vector load),
// DMA h into LDS (L2-bypassing), 128 LDS-fed MFMAs (x half was DMA'd last
// step, cached), gates, publish h + flag (fire-and-forget), then deferred
// out-stores and the x-DMA for the next step.
__launch_bounds__(256, 1)
__global__ void lstm_persist(const float* __restrict__ c0, float* out,
                             char* __restrict__ ws) {
    __shared__ __bf16 xbuf[32768];              // x frags, 64 KB (cached DMA)
    __shared__ __bf16 hbuf[32768];              // h frags, 64 KB (coherent DMA)
    __shared__ float gl[4][16][66];             // [gate][unit][batch] exchange
    __shared__ __bf16 hstage[4][2][16][8];      // [nblk][lq][l16][j]

    const __bf16* W = (const __bf16*)(ws + OFF_W);
    const float* bias = (const float*)(ws + OFF_BIAS);
    __bf16* Hswz = (__bf16*)(ws + OFF_HSWZ);    // [2][32768 elements]
    const __bf16* Xswz = (const __bf16*)(ws + OFF_XSWZ);
    unsigned* flags = (unsigned*)(ws + OFF_BAR);

    const int tid = threadIdx.x;
    const int wave = tid >> 6;      // gate type
    const int lane = tid & 63;
    const int l16 = lane & 15;
    const int quad = lane >> 4;
    const int wg = blockIdx.x;

    // ---- A-fragments resident: ks 0..15 = W_ih cols, 16..31 = W_hh (128 VGPRs)
    bf16x8 A[32];
    {
        const size_t arow = (size_t)(wave * H_ + wg * 16 + l16) * K_ + quad * 8;
        #pragma unroll
        for (int ks = 0; ks < 32; ++ks)
            A[ks] = *(const bf16x8*)(W + arow + ks * 32);
    }

    // ---- cell state in registers: thread owns unit u = tid&15, batches rep*16+(tid>>4)
    const int cu_u = tid & 15;
    const int cu_b0 = tid >> 4;
    const int hu = wg * 16 + cu_u;
    float creg[4];
    #pragma unroll
    for (int rep = 0; rep < 4; ++rep)
        creg[rep] = c0[(size_t)(rep * 16 + cu_b0) * H_ + hu];
    const float bias_i = bias[hu];
    const float bias_f = bias[H_ + hu];
    const float bias_g = bias[2 * H_ + hu];
    const float bias_o = bias[3 * H_ + hu];
    const int lq = cu_u >> 3, jj = cu_u & 7;    // hstage producer coords

    // ---- x-DMA for t=511 (cached); completion covered by first in-loop vmcnt(0)
    {
        const __bf16* xb = Xswz + (size_t)(T_ - 1) * 32768;
        #pragma unroll
        for (int i = 0; i < 16; ++i) {
            const int n = wave * 16 + i;
            __builtin_amdgcn_global_load_lds(
                (const __attribute__((address_space(1))) void*)(xb + (size_t)n * 512 + lane * 8),
                (__attribute__((address_space(3))) void*)(xbuf + n * 512),
                16, 0, 0);
        }
    }

    for (int t = T_ - 1; ; --t) {
        // ---- wait for all 32 producers of h_{t+1} (skip for the first step)
        if (t < T_ - 1) {
            if (tid < 64) {
                const unsigned target = (unsigned)(T_ - 1 - t);
                const unsigned long long faddr =
                    (unsigned long long)(uintptr_t)(flags + (lane & 31));
                unsigned cur;
                do {
                    asm volatile("global_load_dword %0, %1, off sc0 sc1\n\t"
                                 "s_waitcnt vmcnt(0)"
                                 : "=v"(cur) : "v"(faddr) : "memory");
                } while (!__all(lane >= 32 || cur >= target));
            }
            __syncthreads();
        }

        // ---- DMA h_{t+1} frags into LDS: 64 x 1KB, L2-bypassing (sc0|sc1)
        {
            const __bf16* hb = Hswz + (size_t)((t + 1) & 1) * 32768;
            #pragma unroll
            for (int i = 0; i < 16; ++i) {
                const int n = wave * 16 + i;
                __builtin_amdgcn_global_load_lds(
                    (const __attribute__((address_space(1))) void*)(hb + (size_t)n * 512 + lane * 8),
                    (__attribute__((address_space(3))) void*)(hbuf + n * 512),
                    16, 0, 0x11);
            }
        }
        asm volatile("s_waitcnt vmcnt(0)" ::: "memory");
        __syncthreads();

        // ---- 128 MFMAs, all operands from LDS (x: A[0..15], h: A[16..31])
        f32x4 acc[4] = {{0,0,0,0},{0,0,0,0},{0,0,0,0},{0,0,0,0}};
        #pragma unroll
        for (int f = 0; f < 64; ++f) {
            bf16x8 b = *(const bf16x8*)(xbuf + f * 512 + lane * 8);
            acc[f & 3] = __builtin_amdgcn_mfma_f32_16x16x32_bf16(A[f >> 2], b, acc[f & 3], 0, 0, 0);
        }
        #pragma unroll
        for (int f = 0; f < 64; ++f) {
            bf16x8 b = *(const bf16x8*)(hbuf + f * 512 + lane * 8);
            acc[f & 3] = __builtin_amdgcn_mfma_f32_16x16x32_bf16(A[16 + (f >> 2)], b, acc[f & 3], 0, 0, 0);
        }

        // ---- exchange gates: col(batch) = lane&15 (+16*nt), row(unit) = quad*4 + reg
        #pragma unroll
        for (int r = 0; r < 4; ++r)
            #pragma unroll
            for (int nt = 0; nt < 4; ++nt)
                gl[wave][quad * 4 + r][nt * 16 + l16] = acc[nt][r];
        __syncthreads();

        // ---- gates -> cn/hn (registers); stage hn for publish
        float cn_r[4], hn_r[4];
        #pragma unroll
        for (int rep = 0; rep < 4; ++rep) {
            int b = rep * 16 + cu_b0;
            float ig = sigmoid_f(gl[0][cu_u][b] + bias_i);
            float fg = sigmoid_f(gl[1][cu_u][b] + bias_f);
            float gg = tanh_f(gl[2][cu_u][b] + bias_g);
            float og = sigmoid_f(gl[3][cu_u][b] + bias_o);
            float cn = fg * creg[rep] + ig * gg;
            creg[rep] = cn;
            cn_r[rep] = cn;
            float hn = og * tanh_f(cn);
            hn_r[rep] = hn;
            hstage[b >> 4][lq][b & 15][jj] = (__bf16)hn;
        }
        __syncthreads();   // hstage complete

        if (t != 0) {
            // ---- publish h_t frags: sc0 sc1 stores, then drain, then flag
            if (tid < 128) {
                i32x4 v = *(i32x4*)((__bf16*)hstage + tid * 8);
                const int nblk = tid >> 5, lqc = (tid >> 4) & 1, l16c = tid & 15;
                const int hk = wg >> 1, q0 = (wg & 1) * 2;
                size_t off = (size_t)(((hk * 4 + nblk) * 64 + (q0 + lqc) * 16 + l16c)) * 8;
                __bf16* dst = Hswz + (size_t)(t & 1) * 32768 + off;
                asm volatile("global_store_dwordx4 %0, %1, off sc0 sc1"
                             :: "v"(dst), "v"(v) : "memory");
            }
            asm volatile("s_waitcnt vmcnt(0)" ::: "memory");   // per-wave drain
            __syncthreads();                                    // all waves drained
            if (tid == 0) {
                const unsigned val = (unsigned)(T_ - t);
                const unsigned long long faddr =
                    (unsigned long long)(uintptr_t)(flags + wg);
                asm volatile("global_store_dword %0, %1, off sc0 sc1"
                             :: "v"(faddr), "v"(val) : "memory");   // fire-and-forget
            }
        }

        // ---- deferred: out stores (lazy, L2-dirty is fine) and finalization
        float* outt = out + (size_t)t * (B_ * H_);
        #pragma unroll
        for (int rep = 0; rep < 4; ++rep) {
            int b = rep * 16 + cu_b0;
            outt[(size_t)b * H_ + hu] = hn_r[rep];
            if (t == 0) {
                out[(size_t)T_ * B_ * H_ + (size_t)b * H_ + hu] = hn_r[rep];            // h_f
                out[(size_t)T_ * B_ * H_ + B_ * H_ + (size_t)b * H_ + hu] = cn_r[rep];  // c_f
            }
        }

        if (t == 0) break;

        // ---- x-DMA for step t-1 (cached); hidden under next poll + h-DMA
        {
            const __bf16* xb = Xswz + (size_t)(t - 1) * 32768;
            #pragma unroll
            for (int i = 0; i < 16; ++i) {
                const int n = wave * 16 + i;
                __builtin_amdgcn_global_load_lds(
                    (const __attribute__((address_space(1))) void*)(xb + (size_t)n * 512 + lane * 8),
                    (__attribute__((address_space(3))) void*)(xbuf + n * 512),
                    16, 0, 0);
            }
        }
    }
}

extern "C" void kernel_launch(void* const* d_in, const int* in_sizes, int n_in,
                              void* d_out, int out_size, void* d_ws, size_t ws_size,
                              hipStream_t stream) {
    const float* input = (const float*)d_in[0];
    const float* h0   = (const float*)d_in[1];
    const float* c0   = (const float*)d_in[2];
    const float* W_ih = (const float*)d_in[3];
    const float* W_hh = (const float*)d_in[4];
    const float* b_ih = (const float*)d_in[5];
    const float* b_hh = (const float*)d_in[6];
    float* out = (float*)d_out;
    char* ws = (char*)d_ws;

    prep_w<<<(G_ * K_) / 256, 256, 0, stream>>>(W_ih, W_hh, b_ih, b_hh, ws);
    prep_x<<<(T_ * I_ * B_ / 8) / 256, 256, 0, stream>>>(input, ws);
    prep_h0<<<(H_ / 32) * (B_ / 16) * 64 / 256, 256, 0, stream>>>(h0, ws);
    lstm_persist<<<NBLK, 256, 0, stream>>>(c0, out, ws);
}

// Round 7
// 1577.285 us; speedup vs baseline: 11.3264x; 1.7985x over previous
//
#include <hip/hip_runtime.h>
#include <math.h>
#include <stdint.h>

#define T_ 512
#define B_ 64
#define I_ 512
#define H_ 512
#define G_ 2048   // 4*H
#define K_ 1024   // I + H
#define NMR 32    // unit-group WGs (each owns 16 hidden units)
#define NCOL 4    // batch-column WGs (each owns 16 batches)
#define NBLK (NMR * NCOL)   // 128 persistent workgroups, 1 per CU

typedef __bf16 bf16x8 __attribute__((ext_vector_type(8)));
typedef float f32x4 __attribute__((ext_vector_type(4)));
typedef int i32x4 __attribute__((ext_vector_type(4)));

// Workspace layout (bytes):
//   W bf16 [G_][K_]     : 4 MB    ([W_ih | W_hh], bf16)
//   bias f32 [G_]       : 8 KB
//   hswz bf16 [2][64KB] : 128 KB  (h in MFMA B-frag layout, double-buffered)
//   flags u32 [4][64]   : 1 KB    (per-column, per-unit-group progress flags)
//   xswz bf16 [T][64KB] : 32 MB   (x in MFMA B-frag layout, read cached)
#define OFF_W    ((size_t)0)
#define OFF_BIAS (OFF_W + (size_t)G_ * K_ * 2)
#define OFF_HSWZ (OFF_BIAS + (size_t)G_ * 4)
#define OFF_BAR  (OFF_HSWZ + (size_t)2 * H_ * B_ * 2)
#define OFF_XSWZ (OFF_BAR + 1024)

// B-frag swizzle: frag-slot s = (kblk*4 + nblk)*64 + lane, holding 8 bf16:
//   quad = lane>>4, l16 = lane&15;  b = nblk*16 + l16;  k = kblk*32 + quad*8 + j

__global__ void prep_w(const float* __restrict__ W_ih, const float* __restrict__ W_hh,
                       const float* __restrict__ b_ih, const float* __restrict__ b_hh,
                       char* __restrict__ ws) {
    __bf16* W = (__bf16*)(ws + OFF_W);
    float* bias = (float*)(ws + OFF_BIAS);
    int idx = blockIdx.x * 256 + threadIdx.x;   // over G_*K_ = 2M
    int g = idx >> 10;
    int k = idx & (K_ - 1);
    float v = (k < I_) ? W_ih[g * I_ + k] : W_hh[g * H_ + (k - I_)];
    W[idx] = (__bf16)v;
    if (idx < G_) bias[idx] = b_ih[idx] + b_hh[idx];
    if (idx < 256) ((unsigned*)(ws + OFF_BAR))[idx] = 0u;
}

__global__ void prep_x(const float* __restrict__ input, char* __restrict__ ws) {
    __bf16* xswz = (__bf16*)(ws + OFF_XSWZ);
    int s = blockIdx.x * 256 + threadIdx.x;   // frag-chunk id
    int lane = s & 63;
    int nblk = (s >> 6) & 3;
    int kblk = (s >> 8) & 15;
    int t = s >> 12;
    int b = nblk * 16 + (lane & 15);
    int k = kblk * 32 + (lane >> 4) * 8;
    const float* src = input + ((size_t)t * B_ + b) * I_ + k;
    float4 v0 = *(const float4*)src;
    float4 v1 = *(const float4*)(src + 4);
    bf16x8 o;
    o[0]=(__bf16)v0.x; o[1]=(__bf16)v0.y; o[2]=(__bf16)v0.z; o[3]=(__bf16)v0.w;
    o[4]=(__bf16)v1.x; o[5]=(__bf16)v1.y; o[6]=(__bf16)v1.z; o[7]=(__bf16)v1.w;
    *(bf16x8*)(xswz + (size_t)s * 8) = o;
}

__global__ void prep_h0(const float* __restrict__ h0, char* __restrict__ ws) {
    __bf16* hswz0 = (__bf16*)(ws + OFF_HSWZ);   // parity 0: read by step t=511
    int s = blockIdx.x * 256 + threadIdx.x;     // 4096 slots
    int lane = s & 63;
    int nblk = (s >> 6) & 3;
    int hk = s >> 8;
    int b = nblk * 16 + (lane & 15);
    int u = hk * 32 + (lane >> 4) * 8;
    const float* src = h0 + (size_t)b * H_ + u;
    float4 v0 = *(const float4*)src;
    float4 v1 = *(const float4*)(src + 4);
    bf16x8 o;
    o[0]=(__bf16)v0.x; o[1]=(__bf16)v0.y; o[2]=(__bf16)v0.z; o[3]=(__bf16)v0.w;
    o[4]=(__bf16)v1.x; o[5]=(__bf16)v1.y; o[6]=(__bf16)v1.z; o[7]=(__bf16)v1.w;
    *(bf16x8*)(hswz0 + (size_t)s * 8) = o;
}

__device__ __forceinline__ float sigmoid_f(float x) { return 1.f / (1.f + __expf(-x)); }
__device__ __forceinline__ float tanh_f(float x) { return 1.f - 2.f / (1.f + __expf(2.f * x)); }

// Persistent reverse scan, 128 WGs x 256 threads (1/CU). WG (m,n) owns hidden
// units [m*16,m*16+16) x batches [n*16,n*16+16); wave = gate type (M=16 rows,
// N=16, K=1024 -> 32 MFMAs/wave/step). A-frags (128 VGPRs) register-resident.
// Columns n are independent barrier domains (poll fan-in = 32 flags).
// h-DMA latency is overlapped with the x-phase via vmcnt(4).
__launch_bounds__(256, 1)
__global__ void lstm_persist(const float* __restrict__ c0, float* out,
                             char* __restrict__ ws) {
    __shared__ __bf16 xbuf[8192];               // 16 x-frags x 512 elem (16 KB)
    __shared__ __bf16 hbuf[8192];               // 16 h-frags (16 KB)
    __shared__ float gl[4][16][17];             // [gate][unit][batch] exchange
    __shared__ __bf16 hstage[2][16][8];         // [lq][l16][j], 512 B

    const __bf16* W = (const __bf16*)(ws + OFF_W);
    const float* bias = (const float*)(ws + OFF_BIAS);
    __bf16* Hswz = (__bf16*)(ws + OFF_HSWZ);    // [2][32768 elements]
    const __bf16* Xswz = (const __bf16*)(ws + OFF_XSWZ);
    unsigned* flags = (unsigned*)(ws + OFF_BAR);

    const int tid = threadIdx.x;
    const int wave = tid >> 6;      // gate type
    const int lane = tid & 63;
    const int l16 = lane & 15;
    const int quad = lane >> 4;
    const int wgM = blockIdx.x & 31;    // unit group
    const int wgN = blockIdx.x >> 5;    // batch column

    // ---- A-fragments resident: ks 0..15 = W_ih cols, 16..31 = W_hh (128 VGPRs)
    bf16x8 A[32];
    {
        const size_t arow = (size_t)(wave * H_ + wgM * 16 + l16) * K_ + quad * 8;
        #pragma unroll
        for (int ks = 0; ks < 32; ++ks)
            A[ks] = *(const bf16x8*)(W + arow + ks * 32);
    }

    // ---- cell state: thread owns (unit u = tid&15, batch bl = tid>>4)
    const int cu_u = tid & 15;
    const int cu_bl = tid >> 4;
    const int hu = wgM * 16 + cu_u;
    const int batch = wgN * 16 + cu_bl;
    float creg = c0[(size_t)batch * H_ + hu];
    const float bias_i = bias[hu];
    const float bias_f = bias[H_ + hu];
    const float bias_g = bias[2 * H_ + hu];
    const float bias_o = bias[3 * H_ + hu];

    // ---- x-DMA for t=511 (cached); 4 frags per wave (kblk = wave*4 + i)
    {
        const __bf16* xb = Xswz + (size_t)(T_ - 1) * 32768;
        #pragma unroll
        for (int i = 0; i < 4; ++i) {
            const int kb = wave * 4 + i;
            __builtin_amdgcn_global_load_lds(
                (const __attribute__((address_space(1))) void*)(xb + (size_t)((kb * 4 + wgN) * 64 + lane) * 8),
                (__attribute__((address_space(3))) void*)(xbuf + kb * 512),
                16, 0, 0);
        }
    }

    for (int t = T_ - 1; ; --t) {
        // ---- wait for this column's 32 producers of h_{t+1}
        if (t < T_ - 1) {
            if (tid < 64) {
                const unsigned target = (unsigned)(T_ - 1 - t);
                const unsigned long long faddr =
                    (unsigned long long)(uintptr_t)(flags + wgN * 64 + (lane & 31));
                unsigned cur;
                do {
                    asm volatile("global_load_dword %0, %1, off sc0 sc1\n\t"
                                 "s_waitcnt vmcnt(0)"
                                 : "=v"(cur) : "v"(faddr) : "memory");
                } while (!__all(lane >= 32 || cur >= target));
            }
            __syncthreads();
        }

        // ---- issue h-DMA (L2-bypassing), then wait only for the older x-DMAs
        {
            const __bf16* hb = Hswz + (size_t)((t + 1) & 1) * 32768;
            #pragma unroll
            for (int i = 0; i < 4; ++i) {
                const int hk = wave * 4 + i;
                __builtin_amdgcn_global_load_lds(
                    (const __attribute__((address_space(1))) void*)(hb + (size_t)((hk * 4 + wgN) * 64 + lane) * 8),
                    (__attribute__((address_space(3))) void*)(hbuf + hk * 512),
                    16, 0, 0x11);
            }
        }
        asm volatile("s_waitcnt vmcnt(4)" ::: "memory");   // x landed (h may fly)
        __syncthreads();

        // ---- x-phase: 16 MFMAs from xbuf (overlaps in-flight h-DMA)
        f32x4 acc = {0, 0, 0, 0};
        #pragma unroll
        for (int f = 0; f < 16; ++f) {
            bf16x8 b = *(const bf16x8*)(xbuf + f * 512 + lane * 8);
            acc = __builtin_amdgcn_mfma_f32_16x16x32_bf16(A[f], b, acc, 0, 0, 0);
        }
        asm volatile("s_waitcnt vmcnt(0)" ::: "memory");   // h landed (this wave)
        __syncthreads();                                    // all waves; xbuf free

        // ---- h-phase: 16 MFMAs from hbuf
        #pragma unroll
        for (int f = 0; f < 16; ++f) {
            bf16x8 b = *(const bf16x8*)(hbuf + f * 512 + lane * 8);
            acc = __builtin_amdgcn_mfma_f32_16x16x32_bf16(A[16 + f], b, acc, 0, 0, 0);
        }

        // ---- exchange gates: col(batch) = lane&15, row(unit) = quad*4 + reg
        #pragma unroll
        for (int r = 0; r < 4; ++r)
            gl[wave][quad * 4 + r][l16] = acc[r];
        __syncthreads();

        // ---- gates -> c/h (one cell per thread); stage hn for publish
        float ig = sigmoid_f(gl[0][cu_u][cu_bl] + bias_i);
        float fg = sigmoid_f(gl[1][cu_u][cu_bl] + bias_f);
        float gg = tanh_f(gl[2][cu_u][cu_bl] + bias_g);
        float og = sigmoid_f(gl[3][cu_u][cu_bl] + bias_o);
        float cn = fg * creg + ig * gg;
        creg = cn;
        float hn = og * tanh_f(cn);
        hstage[cu_u >> 3][cu_bl][cu_u & 7] = (__bf16)hn;
        __syncthreads();   // hstage complete

        if (t != 0) {
            // ---- publish h_t frags (wave 0 only): sc0sc1 stores, drain, flag
            if (tid < 32) {
                i32x4 v = *(i32x4*)((__bf16*)hstage + tid * 8);
                const int lqc = tid >> 4, l16c = tid & 15;
                const int hk = wgM >> 1, q0 = (wgM & 1) * 2;
                size_t off = (size_t)((hk * 4 + wgN) * 64 + (q0 + lqc) * 16 + l16c) * 8;
                __bf16* dst = Hswz + (size_t)(t & 1) * 32768 + off;
                asm volatile("global_store_dwordx4 %0, %1, off sc0 sc1"
                             :: "v"(dst), "v"(v) : "memory");
            }
            asm volatile("s_waitcnt vmcnt(0)" ::: "memory");   // wave0 data drained
            if (tid == 0) {   // same wave as publishers -> ordered, no barrier
                const unsigned val = (unsigned)(T_ - t);
                const unsigned long long faddr =
                    (unsigned long long)(uintptr_t)(flags + wgN * 64 + wgM);
                asm volatile("global_store_dword %0, %1, off sc0 sc1"
                             :: "v"(faddr), "v"(val) : "memory");
            }
        }

        // ---- deferred: out stores (lazy) and finalization
        out[(size_t)t * B_ * H_ + (size_t)batch * H_ + hu] = hn;
        if (t == 0) {
            out[(size_t)T_ * B_ * H_ + (size_t)batch * H_ + hu] = hn;             // h_f
            out[(size_t)T_ * B_ * H_ + B_ * H_ + (size_t)batch * H_ + hu] = cn;   // c_f
            break;
        }

        // ---- x-DMA for step t-1 (cached); hidden under next poll + h-DMA
        {
            const __bf16* xb = Xswz + (size_t)(t - 1) * 32768;
            #pragma unroll
            for (int i = 0; i < 4; ++i) {
                const int kb = wave * 4 + i;
                __builtin_amdgcn_global_load_lds(
                    (const __attribute__((address_space(1))) void*)(xb + (size_t)((kb * 4 + wgN) * 64 + lane) * 8),
                    (__attribute__((address_space(3))) void*)(xbuf + kb * 512),
                    16, 0, 0);
            }
        }
    }
}

extern "C" void kernel_launch(void* const* d_in, const int* in_sizes, int n_in,
                              void* d_out, int out_size, void* d_ws, size_t ws_size,
                              hipStream_t stream) {
    const float* input = (const float*)d_in[0];
    const float* h0   = (const float*)d_in[1];
    const float* c0   = (const float*)d_in[2];
    const float* W_ih = (const float*)d_in[3];
    const float* W_hh = (const float*)d_in[4];
    const float* b_ih = (const float*)d_in[5];
    const float* b_hh = (const float*)d_in[6];
    float* out = (float*)d_out;
    char* ws = (char*)d_ws;

    prep_w<<<(G_ * K_) / 256, 256, 0, stream>>>(W_ih, W_hh, b_ih, b_hh, ws);
    prep_x<<<(T_ * I_ * B_ / 8) / 256, 256, 0, stream>>>(input, ws);
    prep_h0<<<16, 256, 0, stream>>>(h0, ws);
    lstm_persist<<<NBLK, 256, 0, stream>>>(c0, out, ws);
}